// Round 3
// baseline (64.890 us; speedup 1.0000x reference)
//
#include <hip/hip_runtime.h>

// FWHT over last dim (4096) of (x * seed), scaled by 1/64.
// One wave per row, fully-coalesced global access (1 KB contiguous per
// load/store instruction), two swizzled LDS transposes.
//
// Register layout A (load/store): v[4q+c] <-> j = 256q + 4l + c
//   -> reg-index bits cover j bits {0,1,8,9,10,11}
// Register layout B (after LDS pass 1): v[r] <-> j = (l&3) | (r<<2) | ((l>>2)<<8)
//   -> reg-index bits cover j bits {2..7}
// Butterfly stages commute, so phase1 (bits 0,1,8-11) + phase2 (bits 2-7)
// is a complete FWHT. Both phases are the same uniform stride-1..32 network.
//
// LDS swizzle f(a) = a ^ (((a>>8)&7)<<2)  (word addr a = j):
//   pass1 write (b128, q fixed): bank group = (l&7)^(q&7) -> conflict-free
//   pass1 read  (b32,  r fixed): bank = (l&3)|(((r&7)^((l>>2)&7))<<2) -> 2/bank (free)
//   pass2 write = pass1-read pattern; pass2 read = pass1-write pattern.

#define N 4096

typedef float f32x4 __attribute__((ext_vector_type(4)));

__global__ __launch_bounds__(64, 3) void fwht_coal_kernel(
    const float* __restrict__ x,
    const float* __restrict__ seed,
    float* __restrict__ out)
{
    __shared__ float lds[N];              // 16 KB
    const int l = threadIdx.x;
    const long long row = blockIdx.x;

    const f32x4* x4 = reinterpret_cast<const f32x4*>(x + row * (long long)N);
    const f32x4* s4 = reinterpret_cast<const f32x4*>(seed);
    f32x4*       o4 = reinterpret_cast<f32x4*>(out + row * (long long)N);
    f32x4*     lds4 = reinterpret_cast<f32x4*>(lds);

    float v[64];

    // ---- Coalesced load + seed multiply ----
#pragma unroll
    for (int q = 0; q < 16; ++q) {
        f32x4 a = x4[64 * q + l];
        f32x4 b = s4[64 * q + l];
        f32x4 p = a * b;
        v[4 * q + 0] = p[0];
        v[4 * q + 1] = p[1];
        v[4 * q + 2] = p[2];
        v[4 * q + 3] = p[3];
    }

    // ---- Phase 1: butterflies over reg bits (j bits 0,1,8,9,10,11) ----
#pragma unroll
    for (int s = 1; s < 64; s <<= 1) {
#pragma unroll
        for (int m = 0; m < 64; ++m) {
            if (!(m & s)) {
                float p0 = v[m], p1 = v[m | s];
                v[m]     = p0 + p1;
                v[m | s] = p0 - p1;
            }
        }
    }

    // ---- LDS pass 1: layout A -> layout B ----
#pragma unroll
    for (int q = 0; q < 16; ++q) {
        f32x4 t;
        t[0] = v[4 * q + 0]; t[1] = v[4 * q + 1];
        t[2] = v[4 * q + 2]; t[3] = v[4 * q + 3];
        lds4[(64 * q + l) ^ (q & 7)] = t;     // f applied in float4 space
    }
    __syncthreads();
#pragma unroll
    for (int r = 0; r < 64; ++r) {
        int a = (l & 3) | (r << 2) | ((l >> 2) << 8);
        v[r] = lds[a ^ (((l >> 2) & 7) << 2)];
    }

    // ---- Phase 2: butterflies over reg bits (j bits 2..7) ----
#pragma unroll
    for (int s = 1; s < 64; s <<= 1) {
#pragma unroll
        for (int m = 0; m < 64; ++m) {
            if (!(m & s)) {
                float p0 = v[m], p1 = v[m | s];
                v[m]     = p0 + p1;
                v[m | s] = p0 - p1;
            }
        }
    }

    // ---- LDS pass 2: layout B -> layout A ----
    __syncthreads();   // pass-1 reads done before overwrite
#pragma unroll
    for (int r = 0; r < 64; ++r) {
        int a = (l & 3) | (r << 2) | ((l >> 2) << 8);
        lds[a ^ (((l >> 2) & 7) << 2)] = v[r];
    }
    __syncthreads();

    // ---- Coalesced nontemporal store, scaled by 1/64 ----
#pragma unroll
    for (int q = 0; q < 16; ++q) {
        f32x4 t = lds4[(64 * q + l) ^ (q & 7)];
        t *= 0.015625f;
        __builtin_nontemporal_store(t, &o4[64 * q + l]);
    }
}

extern "C" void kernel_launch(void* const* d_in, const int* in_sizes, int n_in,
                              void* d_out, int out_size, void* d_ws, size_t ws_size,
                              hipStream_t stream)
{
    const float* x    = (const float*)d_in[0];
    const float* seed = (const float*)d_in[1];
    float* out        = (float*)d_out;

    const int rows = in_sizes[0] / N;     // 8192
    dim3 grid(rows), block(64);
    fwht_coal_kernel<<<grid, block, 0, stream>>>(x, seed, out);
}

// Round 4
// 43.914 us; speedup vs baseline: 1.4777x; 1.4777x over previous
//
#include <hip/hip_runtime.h>

// FWHT over last dim (4096) of (x * seed), scaled by 1/64.
// One 256-thread block (4 waves) per row sharing ONE 16 KB LDS buffer ->
// 8 blocks/CU (32 waves) occupancy instead of R1-R3's ~10 single-wave blocks.
// 16 regs/thread, three radix-16 register phases over disjoint j-bit groups
// (stages commute): {0,1,10,11} -> {2,3,4,5} -> {6,7,8,9}, with two swizzled
// LDS transposes between phases. Plain (non-nt) global access, fully
// coalesced: loads 1 KB/wave-instr (float4), stores 256 B/wave-instr (dword).
//
// Thread t = 64*w + l.
// Layout A (load):  v[4q+c] <-> j = 1024q + 4t + c      (regs = j bits 0,1,10,11)
// Layout B:         v[r]    <-> j = (l&3)|(r<<2)|((l>>2)<<6)|(w<<10)  (regs = bits 2..5)
// Layout C (store): v[r]    <-> j = l | (r<<6) | (w<<10)              (regs = bits 6..9)
// LDS swizzle f(a) = a ^ (((a>>6)&7)<<2) (word space, bijective):
//   A-write b128: contiguous-permuted -> conflict-free
//   B-read/B-write b32: banks (l&3)|(((r^((l>>2)&7))&7)<<2) -> 2 lanes/bank (free)
//   C-read b32: bank (l&31)^((r&7)<<2) -> 2 lanes/bank (free)
// B-write hits exactly this thread's B-read words (bijective partition) ->
// no barrier needed between them; only 2 __syncthreads total.

#define N 4096

typedef float f32x4 __attribute__((ext_vector_type(4)));

__global__ __launch_bounds__(256, 8) void fwht4w_kernel(
    const float* __restrict__ x,
    const float* __restrict__ seed,
    float* __restrict__ out)
{
    __shared__ float lds[N];              // 16 KB, shared by all 4 waves
    const int t = threadIdx.x;            // 0..255
    const int l = t & 63;
    const int w = t >> 6;
    const long long row = blockIdx.x;

    const f32x4* x4 = reinterpret_cast<const f32x4*>(x + row * (long long)N);
    const f32x4* s4 = reinterpret_cast<const f32x4*>(seed);
    f32x4*     lds4 = reinterpret_cast<f32x4*>(lds);

    float v[16];

    // ---- Coalesced load + seed multiply (layout A) ----
#pragma unroll
    for (int q = 0; q < 4; ++q) {
        f32x4 a = x4[256 * q + t];
        f32x4 b = s4[256 * q + t];
        f32x4 p = a * b;
        v[4*q+0] = p[0]; v[4*q+1] = p[1]; v[4*q+2] = p[2]; v[4*q+3] = p[3];
    }

    // ---- Phase 1: radix-16 over reg bits (j bits 0,1,10,11) ----
#pragma unroll
    for (int s = 1; s < 16; s <<= 1) {
#pragma unroll
        for (int m = 0; m < 16; ++m) {
            if (!(m & s)) {
                float p0 = v[m], p1 = v[m | s];
                v[m] = p0 + p1; v[m | s] = p0 - p1;
            }
        }
    }

    // ---- Transpose 1 write (layout A, swizzled b128) ----
    {
        const int tx = t ^ ((t >> 4) & 7);        // f folded into f4 index
#pragma unroll
        for (int q = 0; q < 4; ++q) {
            f32x4 tv;
            tv[0] = v[4*q+0]; tv[1] = v[4*q+1]; tv[2] = v[4*q+2]; tv[3] = v[4*q+3];
            lds4[256 * q + tx] = tv;
        }
    }
    __syncthreads();

    // ---- Transpose 1 read (layout B, swizzled b32) ----
    const int baseB = (l & 3) | ((l >> 2) << 6) | (w << 10);
    const int kB    = ((l >> 2) & 7) << 2;
#pragma unroll
    for (int r = 0; r < 16; ++r)
        v[r] = lds[(baseB | (r << 2)) ^ kB];

    // ---- Phase 2: radix-16 over reg bits (j bits 2..5) ----
#pragma unroll
    for (int s = 1; s < 16; s <<= 1) {
#pragma unroll
        for (int m = 0; m < 16; ++m) {
            if (!(m & s)) {
                float p0 = v[m], p1 = v[m | s];
                v[m] = p0 + p1; v[m | s] = p0 - p1;
            }
        }
    }

    // ---- Transpose 2 write (layout B, same word set this thread just read:
    //      bijective partition -> no barrier needed before these writes) ----
#pragma unroll
    for (int r = 0; r < 16; ++r)
        lds[(baseB | (r << 2)) ^ kB] = v[r];
    __syncthreads();

    // ---- Transpose 2 read (layout C, swizzled b32) ----
    {
        const int baseC = l | (w << 10);
#pragma unroll
        for (int r = 0; r < 16; ++r)
            v[r] = lds[(baseC | (r << 6)) ^ ((r & 7) << 2)];
    }

    // ---- Phase 3: radix-16 over reg bits (j bits 6..9) ----
#pragma unroll
    for (int s = 1; s < 16; s <<= 1) {
#pragma unroll
        for (int m = 0; m < 16; ++m) {
            if (!(m & s)) {
                float p0 = v[m], p1 = v[m | s];
                v[m] = p0 + p1; v[m | s] = p0 - p1;
            }
        }
    }

    // ---- Coalesced store (layout C), scaled by 1/64 ----
    float* o = out + row * (long long)N;
#pragma unroll
    for (int r = 0; r < 16; ++r)
        o[l | (r << 6) | (w << 10)] = v[r] * 0.015625f;
}

extern "C" void kernel_launch(void* const* d_in, const int* in_sizes, int n_in,
                              void* d_out, int out_size, void* d_ws, size_t ws_size,
                              hipStream_t stream)
{
    const float* x    = (const float*)d_in[0];
    const float* seed = (const float*)d_in[1];
    float* out        = (float*)d_out;

    const int rows = in_sizes[0] / N;     // 8192
    dim3 grid(rows), block(256);
    fwht4w_kernel<<<grid, block, 0, stream>>>(x, seed, out);
}